// Round 12
// baseline (74.257 us; speedup 1.0000x reference)
//
#include <hip/hip_runtime.h>

// DIAGNOSTIC ROUND (r12): r10's algorithm x16 idempotent repeats, to separate
// fixed per-launch overhead from per-pass resident time, and to hoist our
// kernel above the 77us harness fill kernels in the rocprof top-5 so its
// counters become visible. Output is bit-identical to r10 (each rep recomputes
// the same result from scratch; single write at the end).
//
// Per rep: all 8 waves issue their 8x1KB global_load_lds chunks, drain their
// OWN vmcnt(0), barrier; wave 0 runs the 127-step scaled-linear recursion from
// LDS; second barrier keeps rep k+1's DMA from clobbering LDS mid-compute.
// #pragma unroll 1 on the rep loop (inner recursion stays fully unrolled for
// readlane immediates / static ring slots; ~8KB body fits icache).

#define BB 512
#define TT 512
#define CC 128
#define LL 64
#define TU 128   // input_len = C (source bug, replicated)
#define EPSF 1e-7f
#define PD 16    // LDS-read ring depth (power of two)
#define LN2F 0.69314718055994530942f
#define NWAVE 8
#define NREP 16

template <int CTRL>
__device__ __forceinline__ float dpp_f(float x) {
    const int xi = __float_as_int(x);
    return __int_as_float(__builtin_amdgcn_update_dpp(xi, xi, CTRL, 0xF, 0xF, false));
}

__device__ __forceinline__ float shift_up1z(float x) {
    const int xi = __float_as_int(x);
    return __int_as_float(__builtin_amdgcn_update_dpp(xi, xi, 0x138 /*wave_shr:1*/,
                                                      0xF, 0xF, true));
}

__device__ __forceinline__ float wave_max(float v) {
    v = fmaxf(v, dpp_f<0xB1>(v));   // quad_perm [1,0,3,2]
    v = fmaxf(v, dpp_f<0x4E>(v));   // quad_perm [2,3,0,1]
    v = fmaxf(v, dpp_f<0x141>(v));  // row_half_mirror
    v = fmaxf(v, dpp_f<0x140>(v));  // row_mirror
    v = fmaxf(v, dpp_f<0x142>(v));  // row_bcast15
    v = fmaxf(v, dpp_f<0x143>(v));  // row_bcast31
    return __int_as_float(__builtin_amdgcn_readlane(__float_as_int(v), 63));
}

__device__ __forceinline__ void renorm(float& b0, float& b1, float& b2,
                                       int& acc, int lane, int t_done) {
    float m = fmaxf(b0, b1);
    if (lane == 63) m = fmaxf(m, b2);
    m = (lane + 64 >= t_done) ? m : 0.0f;
    const float M = wave_max(m);
    int e = 0;
    (void)frexpf(M, &e);
    const float scale = ldexpf(1.0f, -e);
    b0 *= scale; b1 *= scale; b2 *= scale;
    acc += e;
}

__global__ __launch_bounds__(NWAVE * 64) void ctc_rep(const int* __restrict__ y_true,
                                                      const float* __restrict__ y_pred,
                                                      float* __restrict__ out) {
    __shared__ float lds[TU * CC];          // 64 KB
    const int b = blockIdx.x;
    const int tid = threadIdx.x;
    const int wid = tid >> 6;
    const int lane = tid & 63;
    const float* yp = y_pred + (size_t)b * TT * CC;

    const int lbl  = y_true[b * LL + lane];
    const int lblp = __shfl_up(lbl, 1);
    const float skipf = (lane >= 1 && lbl != lblp) ? 1.0f : 0.0f;

    float outv = 0.0f;

#pragma unroll 1
    for (int rep = 0; rep < NREP; ++rep) {
        // Cooperative DMA: every wave issues its 8x1KB pieces, drains its own
        // vmcnt, then one barrier => whole 64KB slab resident.
        {
            auto ldsb = (__attribute__((address_space(3))) unsigned int*)lds;
            auto gb   = (const __attribute__((address_space(1))) unsigned int*)yp;
#pragma unroll
            for (int r = 0; r < 64 / NWAVE; ++r) {
                const int i = wid * (64 / NWAVE) + r;
                __builtin_amdgcn_global_load_lds(gb + i * 256 + lane * 4,
                                                 ldsb + i * 256, 16, 0, 0);
            }
        }
        asm volatile("s_waitcnt vmcnt(0)" ::: "memory");
        __syncthreads();

        if (wid == 0) {
            const float pbr0e = lds[lane * CC + (CC - 1)] + EPSF;
            const float pbr1e = lds[(64 + lane) * CC + (CC - 1)] + EPSF;

            float plr[PD];
#pragma unroll
            for (int j = 0; j < PD; ++j) plr[j] = lds[(1 + j) * CC + lbl];

            const float pl0 = lds[lbl] + EPSF;
            const float pb0 = __int_as_float(
                __builtin_amdgcn_readlane(__float_as_int(pbr0e), 0));
            float b0 = (lane == 0) ? pb0 : 0.0f;
            float b1 = (lane == 0) ? pl0 : 0.0f;
            float b2 = 0.0f;
            int acc = 0;

#pragma unroll
            for (int t = 1; t < TU; ++t) {
                const int slot = (t - 1) & (PD - 1);
                const float plv = plr[slot];
                const int trow = (t + PD < TU) ? (t + PD) : (TU - 1);
                plr[slot] = lds[trow * CC + lbl];
                const float ple = plv + EPSF;
                const float pbe = __int_as_float(__builtin_amdgcn_readlane(
                    __float_as_int((t < 64) ? pbr0e : pbr1e), t & 63));
                const float b1p = shift_up1z(b1);
                const float nb0 = (b0 + b1p) * pbe;
                const float h   = __builtin_fmaf(skipf, b1p, b1);
                const float nb1 = (b0 + h) * ple;
                const float nb2 = (b2 + b1) * pbe;
                b0 = nb0; b1 = nb1; b2 = nb2;
                if ((t & 7) == 0) renorm(b0, b1, b2, acc, lane, t);
            }

            const float s = b1 + b2;               // states 127, 128
            outv = -LN2F * (__log2f(s) + (float)acc);
        }
        __syncthreads();   // LDS safe before next rep's DMA
    }

    if (wid == 0 && lane == 63) out[b] = outv;
}

extern "C" void kernel_launch(void* const* d_in, const int* in_sizes, int n_in,
                              void* d_out, int out_size, void* d_ws, size_t ws_size,
                              hipStream_t stream) {
    const int*   y_true = (const int*)d_in[0];
    const float* y_pred = (const float*)d_in[1];
    float*       out    = (float*)d_out;
    (void)in_sizes; (void)n_in; (void)out_size; (void)d_ws; (void)ws_size;

    ctc_rep<<<BB, NWAVE * 64, 0, stream>>>(y_true, y_pred, out);
}

// Round 13
// 11.617 us; speedup vs baseline: 6.3921x; 6.3921x over previous
//
#include <hip/hip_runtime.h>

// CTC batch cost, faithful port of the JAX reference (incl. the input_len = C
// source bug). B=512, T=512, C=128, L=64 -> S=129 states, TU=128 time steps.
//
// r13 = r10 skeleton + serial-chain micro-opts. Evidence base (r12 diag):
// fixed replay overhead F ~= 7.2us; warm pass ~= 4.2us; pass time invariant
// to HBM-vs-L3 source => structure-bound, attack the serial chain.
//   - One block (8 waves) per batch; waves cooperatively DMA the 64 KB slab
//     into LDS (global_load_lds, no VGPR dests), own-vmcnt drain + 1 barrier.
//   - Wave 0 runs the 127-step scaled-LINEAR recursion from LDS; waves 1-7
//     exit. Critical cycle shortened by fma re-association:
//       h   = fma(skipf, b1p, b1)          b1p = dpp wave_shr:1 of b1
//       nb1 = fma(h, ple, b0*ple)          (b0*ple off prev-step b0: early)
//       nb0 = fma(b1p, pbe, b0*pbe)
//       nb2 = fma(b1, pbe, b2*pbe)         (state 128, lane-63 local)
//     => b1 recurrence = dpp + fma + fma (~10-12 cy) vs add+add+mul (~16).
//   - Label probs: 32-deep ds_read register ring (static slots, full unroll)
//     -- 2x the latency headroom of r10's 16 (3-way-conflict gathers ~6cy
//     throughput, ~120cy latency).
//   - Blank col pre-eps'd in 2 VGPRs, readlane-immediate broadcast per step.
//   - Renorm every 8 steps: wave max (DPP butterfly, tail-reachability mask),
//     exact power-of-2 scale via frexp/ldexp, int exponent accumulator.
// loss = -ln2 * (log2(b1+b2) + acc) at lane 63.

#define BB 512
#define TT 512
#define CC 128
#define LL 64
#define TU 128   // input_len = C (source bug, replicated)
#define EPSF 1e-7f
#define PD 32    // LDS-read ring depth (power of two)
#define LN2F 0.69314718055994530942f
#define NWAVE 8

template <int CTRL>
__device__ __forceinline__ float dpp_f(float x) {
    const int xi = __float_as_int(x);
    return __int_as_float(__builtin_amdgcn_update_dpp(xi, xi, CTRL, 0xF, 0xF, false));
}

// whole-wave shift-up-by-1 with zero fill into lane 0: one v_mov_dpp.
__device__ __forceinline__ float shift_up1z(float x) {
    const int xi = __float_as_int(x);
    return __int_as_float(__builtin_amdgcn_update_dpp(xi, xi, 0x138 /*wave_shr:1*/,
                                                      0xF, 0xF, true));
}

// wave-wide max via DPP butterfly; global max in lane 63, broadcast via readlane.
__device__ __forceinline__ float wave_max(float v) {
    v = fmaxf(v, dpp_f<0xB1>(v));   // quad_perm [1,0,3,2]
    v = fmaxf(v, dpp_f<0x4E>(v));   // quad_perm [2,3,0,1]
    v = fmaxf(v, dpp_f<0x141>(v));  // row_half_mirror
    v = fmaxf(v, dpp_f<0x140>(v));  // row_mirror
    v = fmaxf(v, dpp_f<0x142>(v));  // row_bcast15
    v = fmaxf(v, dpp_f<0x143>(v));  // row_bcast31
    return __int_as_float(__builtin_amdgcn_readlane(__float_as_int(v), 63));
}

__device__ __forceinline__ void renorm(float& b0, float& b1, float& b2,
                                       int& acc, int lane, int t_done) {
    float m = fmaxf(b0, b1);
    if (lane == 63) m = fmaxf(m, b2);
    m = (lane + 64 >= t_done) ? m : 0.0f;   // only tail-reachable lanes matter
    const float M = wave_max(m);
    int e = 0;
    (void)frexpf(M, &e);                    // native v_frexp_exp; frexpf(0)->e=0
    const float scale = ldexpf(1.0f, -e);   // exact power of two
    b0 *= scale; b1 *= scale; b2 *= scale;
    acc += e;
}

__global__ __launch_bounds__(NWAVE * 64) void ctc_wave(const int* __restrict__ y_true,
                                                       const float* __restrict__ y_pred,
                                                       float* __restrict__ out) {
    __shared__ float lds[TU * CC];          // 64 KB: rows 0..127 of this batch
    const int b = blockIdx.x;
    const int tid = threadIdx.x;
    const int wid = tid >> 6;
    const int lane = tid & 63;
    const float* yp = y_pred + (size_t)b * TT * CC;

    // Cooperative DMA: 64 x 1KB global->LDS spread over 8 waves, no VGPR
    // destinations. Own-vmcnt drain per wave + one barrier => slab resident.
    {
        auto ldsb = (__attribute__((address_space(3))) unsigned int*)lds;
        auto gb   = (const __attribute__((address_space(1))) unsigned int*)yp;
#pragma unroll
        for (int r = 0; r < 64 / NWAVE; ++r) {
            const int i = wid * (64 / NWAVE) + r;   // 1KB chunk index
            __builtin_amdgcn_global_load_lds(gb + i * 256 + lane * 4,
                                             ldsb + i * 256, 16, 0, 0);
        }
    }

    const int lbl  = y_true[b * LL + lane];   // label for state 2*lane+1
    const int lblp = __shfl_up(lbl, 1);       // one-time, off the hot loop
    const float skipf = (lane >= 1 && lbl != lblp) ? 1.0f : 0.0f;

    asm volatile("s_waitcnt vmcnt(0)" ::: "memory");
    __syncthreads();
    if (wid != 0) return;                   // waves 1-7 were DMA-only

    // Blank column (lane-uniform per t), pre-eps'd, register-resident.
    const float pbr0e = lds[lane * CC + (CC - 1)] + EPSF;
    const float pbr1e = lds[(64 + lane) * CC + (CC - 1)] + EPSF;

    // Label-prob ring for t = 1..PD from LDS.
    float plr[PD];
#pragma unroll
    for (int j = 0; j < PD; ++j) plr[j] = lds[(1 + j) * CC + lbl];

    // t = 0 init (linear space): states 0,1 = p + eps; everything else 0.
    const float pl0 = lds[lbl] + EPSF;
    const float pb0 = __int_as_float(__builtin_amdgcn_readlane(__float_as_int(pbr0e), 0));
    float b0 = (lane == 0) ? pb0 : 0.0f;
    float b1 = (lane == 0) ? pl0 : 0.0f;
    float b2 = 0.0f;
    int acc = 0;

#pragma unroll
    for (int t = 1; t < TU; ++t) {
        const int slot = (t - 1) & (PD - 1);       // compile-time under unroll
        const float plv = plr[slot];
        const int trow = (t + PD < TU) ? (t + PD) : (TU - 1);  // clamp, dead past end
        plr[slot] = lds[trow * CC + lbl];          // refill for step t+PD
        const float ple = plv + EPSF;
        const float pbe = __int_as_float(__builtin_amdgcn_readlane(
            __float_as_int((t < 64) ? pbr0e : pbr1e), t & 63));
        // early products off prev-step b0/b2 (off the b1 recurrence cycle)
        const float t0 = b0 * pbe;
        const float t1 = b0 * ple;
        const float t2 = b2 * pbe;
        const float b1p = shift_up1z(b1);
        const float h   = __builtin_fmaf(skipf, b1p, b1);
        const float nb0 = __builtin_fmaf(b1p, pbe, t0);
        const float nb1 = __builtin_fmaf(h,   ple, t1);
        const float nb2 = __builtin_fmaf(b1,  pbe, t2);
        b0 = nb0; b1 = nb1; b2 = nb2;
        if ((t & 7) == 0) renorm(b0, b1, b2, acc, lane, t);
    }

    if (lane == 63) {
        const float s = b1 + b2;                   // states 127, 128
        out[b] = -LN2F * (__log2f(s) + (float)acc);
    }
}

extern "C" void kernel_launch(void* const* d_in, const int* in_sizes, int n_in,
                              void* d_out, int out_size, void* d_ws, size_t ws_size,
                              hipStream_t stream) {
    const int*   y_true = (const int*)d_in[0];
    const float* y_pred = (const float*)d_in[1];
    float*       out    = (float*)d_out;
    (void)in_sizes; (void)n_in; (void)out_size; (void)d_ws; (void)ws_size;

    ctc_wave<<<BB, NWAVE * 64, 0, stream>>>(y_true, y_pred, out);
}